// Round 10
// baseline (120.222 us; speedup 1.0000x reference)
//
#include <hip/hip_runtime.h>

#define BB 512
#define SS 512
#define TT 64
#define TSTRIDE 66   // transitions is (66,66)

typedef _Float16 h2 __attribute__((ext_vector_type(2)));
typedef int i2v __attribute__((ext_vector_type(2)));

static __device__ __forceinline__ float first_lane(float v) {
    return __int_as_float(__builtin_amdgcn_readfirstlane(__float_as_int(v)));
}
static __device__ __forceinline__ unsigned pk_f16(float a, float b) {
    return __builtin_bit_cast(unsigned, __builtin_amdgcn_cvt_pkrtz(a, b));
}
static __device__ __forceinline__ h2 as_h2(unsigned u) {
    return __builtin_bit_cast(h2, u);
}
static __device__ __forceinline__ unsigned bperm(int addr, unsigned v) {
    return (unsigned)__builtin_amdgcn_ds_bpermute(addr, (int)v);
}
#define FDOT2(a, b, c) __builtin_amdgcn_fdot2((a), (b), (c), false)
#define DPPF(v, ctrl) __int_as_float(__builtin_amdgcn_mov_dpp(__float_as_int(v), (ctrl), 0xF, 0xF, true))
#define DPPU(v, ctrl) ((unsigned)__builtin_amdgcn_mov_dpp((int)(v), (ctrl), 0xF, 0xF, true))
#define SWZ16(v) ((unsigned)__builtin_amdgcn_ds_swizzle((int)(v), 0x401F))   // lane ^= 16

#define DO32(F) F(0) F(1) F(2) F(3) F(4) F(5) F(6) F(7) \
                F(8) F(9) F(10) F(11) F(12) F(13) F(14) F(15) \
                F(16) F(17) F(18) F(19) F(20) F(21) F(22) F(23) \
                F(24) F(25) F(26) F(27) F(28) F(29) F(30) F(31)

// Meet-in-the-middle (R9) + pure-VALU p-broadcast (R10).
// Received-value index algebra: W_k[l] = {p[l^tl(k)], p[l^tl(k)^1]},
// tl = {0,2,7,5,15,13,8,10} built from quad_perm/half_mirror/mirror DPP;
// X_k = W_k[l^16] (ds_swizzle 0x401F), Y_k = W_k[l^32] (permlane32_swap),
// Z_k = X_k[l^32] = W_k[l^48]. E slot (g,k) at lane j pre-permuted at init:
// i = j ^ (g<<4) ^ tl(k) (fwd: E[i][j]; bwd: E[j][i]).
__global__ __launch_bounds__(64)
__attribute__((amdgpu_waves_per_eu(1, 1)))
void crf_scan2_kernel(
    const float* __restrict__ emissions,   // [B,S,T]
    const float* __restrict__ mask,        // [B,S]
    const float* __restrict__ trans,       // [66,66]
    float* __restrict__ ws_state)          // [B][128]: F[64] then U[64]
{
    __shared__ unsigned EQ[32][64];        // 8 KB E-fragment staging

    const int blk = blockIdx.x;
    const int b   = blk >> 1;
    const int dir = blk & 1;
    const int j   = threadIdx.x;   // 0..63
    const bool lo32 = (j < 32);
    const int a32v = ((j ^ 32) << 2);      // bpermute fallback address

    const float* em = emissions + (size_t)b * SS * TT;
    const float* mk = mask + (size_t)b * SS;

    // ---- E fragments, pre-permuted to the broadcast delivery order ----
    {
        const int tl[8] = {0, 2, 7, 5, 15, 13, 8, 10};
        #pragma unroll
        for (int w = 0; w < 32; ++w) {
            int g = w >> 3, k = w & 7;
            int i0 = j ^ (g << 4) ^ tl[k];
            int i1 = i0 ^ 1;
            if (dir == 0)
                EQ[w][j] = pk_f16(__expf(trans[i0 * TSTRIDE + j]),
                                  __expf(trans[i1 * TSTRIDE + j]));
            else
                EQ[w][j] = pk_f16(__expf(trans[j * TSTRIDE + i0]),
                                  __expf(trans[j * TSTRIDE + i1]));
        }
    }
    __syncthreads();

#define CDECL(K) const unsigned c##K = EQ[K][j];
    DO32(CDECL)
#undef CDECL

#if defined(__has_builtin) && __has_builtin(__builtin_amdgcn_permlane32_swap)
#define XCH32(DST, SRC) { i2v r_ = __builtin_amdgcn_permlane32_swap((int)(SRC), (int)(SRC), false, false); \
                          DST = (unsigned)(lo32 ? r_.y : r_.x); }
#else
#define XCH32(DST, SRC) { DST = bperm(a32v, (SRC)); }
#endif

    // PRE folds inside the exp (bwd emission), POST adds after log (fwd).
#define STEPC(PRE, POST, CADD) do { \
        float m0c = first_lane(sc) + (CADD); \
        float p   = __expf(sc + (PRE) - m0c); \
        float pn_ = DPPF(p, 0xB1); \
        unsigned W0 = pk_f16(p, pn_); \
        unsigned W1 = DPPU(W0, 0x4E); \
        unsigned W2 = DPPU(W0, 0x141); \
        unsigned W3 = DPPU(W1, 0x141); \
        unsigned W4 = DPPU(W0, 0x140); \
        unsigned W5 = DPPU(W1, 0x140); \
        unsigned W6 = DPPU(W4, 0x141); \
        unsigned W7 = DPPU(W5, 0x141); \
        unsigned X0 = SWZ16(W0), X1 = SWZ16(W1), X2 = SWZ16(W2), X3 = SWZ16(W3); \
        unsigned X4 = SWZ16(W4), X5 = SWZ16(W5), X6 = SWZ16(W6), X7 = SWZ16(W7); \
        unsigned Y0, Y1, Y2, Y3, Y4, Y5, Y6, Y7; \
        XCH32(Y0, W0) XCH32(Y1, W1) XCH32(Y2, W2) XCH32(Y3, W3) \
        XCH32(Y4, W4) XCH32(Y5, W5) XCH32(Y6, W6) XCH32(Y7, W7) \
        float a0_ = 0.f, a1_ = 0.f, a2_ = 0.f, a3_ = 0.f; \
        a0_ = FDOT2(as_h2(W0), as_h2(c0), a0_); \
        a1_ = FDOT2(as_h2(W1), as_h2(c1), a1_); \
        a2_ = FDOT2(as_h2(W2), as_h2(c2), a2_); \
        a3_ = FDOT2(as_h2(W3), as_h2(c3), a3_); \
        a0_ = FDOT2(as_h2(W4), as_h2(c4), a0_); \
        a1_ = FDOT2(as_h2(W5), as_h2(c5), a1_); \
        a2_ = FDOT2(as_h2(W6), as_h2(c6), a2_); \
        a3_ = FDOT2(as_h2(W7), as_h2(c7), a3_); \
        a0_ = FDOT2(as_h2(Y0), as_h2(c16), a0_); \
        a1_ = FDOT2(as_h2(Y1), as_h2(c17), a1_); \
        a2_ = FDOT2(as_h2(Y2), as_h2(c18), a2_); \
        a3_ = FDOT2(as_h2(Y3), as_h2(c19), a3_); \
        a0_ = FDOT2(as_h2(Y4), as_h2(c20), a0_); \
        a1_ = FDOT2(as_h2(Y5), as_h2(c21), a1_); \
        a2_ = FDOT2(as_h2(Y6), as_h2(c22), a2_); \
        a3_ = FDOT2(as_h2(Y7), as_h2(c23), a3_); \
        unsigned Z0, Z1, Z2, Z3, Z4, Z5, Z6, Z7; \
        XCH32(Z0, X0) XCH32(Z1, X1) XCH32(Z2, X2) XCH32(Z3, X3) \
        XCH32(Z4, X4) XCH32(Z5, X5) XCH32(Z6, X6) XCH32(Z7, X7) \
        a0_ = FDOT2(as_h2(X0), as_h2(c8),  a0_); \
        a1_ = FDOT2(as_h2(X1), as_h2(c9),  a1_); \
        a2_ = FDOT2(as_h2(X2), as_h2(c10), a2_); \
        a3_ = FDOT2(as_h2(X3), as_h2(c11), a3_); \
        a0_ = FDOT2(as_h2(X4), as_h2(c12), a0_); \
        a1_ = FDOT2(as_h2(X5), as_h2(c13), a1_); \
        a2_ = FDOT2(as_h2(X6), as_h2(c14), a2_); \
        a3_ = FDOT2(as_h2(X7), as_h2(c15), a3_); \
        a0_ = FDOT2(as_h2(Z0), as_h2(c24), a0_); \
        a1_ = FDOT2(as_h2(Z1), as_h2(c25), a1_); \
        a2_ = FDOT2(as_h2(Z2), as_h2(c26), a2_); \
        a3_ = FDOT2(as_h2(Z3), as_h2(c27), a3_); \
        a0_ = FDOT2(as_h2(Z4), as_h2(c28), a0_); \
        a1_ = FDOT2(as_h2(Z5), as_h2(c29), a1_); \
        a2_ = FDOT2(as_h2(Z6), as_h2(c30), a2_); \
        a3_ = FDOT2(as_h2(Z7), as_h2(c31), a3_); \
        sc = m0c + __logf((a0_ + a1_) + (a2_ + a3_)) + (POST); \
    } while (0)

    float sc;
    if (dir == 0) {
        // ---------- forward: steps 1..255, no mask (len >= 256) ----------
        sc = em[j] + trans[j * TSTRIDE + TT];   // score0 (mask[0]==1)
        float r0 = em[1 * TT + j], r1 = em[2 * TT + j];
        float r2 = em[3 * TT + j], r3 = em[4 * TT + j];
        float r4 = em[5 * TT + j], r5 = em[6 * TT + j];
        float r6 = em[7 * TT + j], r7 = em[8 * TT + j];
        const float* pe = em + 9 * TT + j;
        for (int it = 0; it < 31; ++it) {       // steps 1..248
            float n0 = pe[0],   n1 = pe[64],  n2 = pe[128], n3 = pe[192];
            float n4 = pe[256], n5 = pe[320], n6 = pe[384], n7 = pe[448];
            pe += 512;
            STEPC(0.0f, r0, 4.0f); STEPC(0.0f, r1, 4.0f);
            STEPC(0.0f, r2, 4.0f); STEPC(0.0f, r3, 4.0f);
            STEPC(0.0f, r4, 4.0f); STEPC(0.0f, r5, 4.0f);
            STEPC(0.0f, r6, 4.0f); STEPC(0.0f, r7, 4.0f);
            r0 = n0; r1 = n1; r2 = n2; r3 = n3;
            r4 = n4; r5 = n5; r6 = n6; r7 = n7;
        }
        STEPC(0.0f, r0, 4.0f); STEPC(0.0f, r1, 4.0f);   // steps 249..255
        STEPC(0.0f, r2, 4.0f); STEPC(0.0f, r3, 4.0f);
        STEPC(0.0f, r4, 4.0f); STEPC(0.0f, r5, 4.0f);
        STEPC(0.0f, r6, 4.0f);
        ws_state[(size_t)b * 128 + j] = sc;
    } else {
        // ---------- backward: steps 511..256 ----------
        float msum = 0.f;
        #pragma unroll
        for (int t = 0; t < 8; ++t) msum += mk[j + 64 * t];
        #pragma unroll
        for (int off = 32; off; off >>= 1) msum += __shfl_xor(msum, off);
        const int len = (int)(first_lane(msum) + 0.5f);

        sc = trans[65 * TSTRIDE + j];           // u_511 = stop vector
        float r0 = em[511 * TT + j], r1 = em[510 * TT + j];
        float r2 = em[509 * TT + j], r3 = em[508 * TT + j];
        float r4 = em[507 * TT + j], r5 = em[506 * TT + j];
        float r6 = em[505 * TT + j], r7 = em[504 * TT + j];
        const float* pe = em + 503 * TT + j;
        int scur = 511;
#define BEE(RK, SV) (((SV) < len) ? (RK) : 0.0f)
        for (int it = 0; it < 31; ++it) {       // steps 511..264
            float n0 = pe[0],    n1 = pe[-64],  n2 = pe[-128], n3 = pe[-192];
            float n4 = pe[-256], n5 = pe[-320], n6 = pe[-384], n7 = pe[-448];
            pe -= 512;
            STEPC(BEE(r0, scur - 0), 0.0f, 5.0f);
            STEPC(BEE(r1, scur - 1), 0.0f, 5.0f);
            STEPC(BEE(r2, scur - 2), 0.0f, 5.0f);
            STEPC(BEE(r3, scur - 3), 0.0f, 5.0f);
            STEPC(BEE(r4, scur - 4), 0.0f, 5.0f);
            STEPC(BEE(r5, scur - 5), 0.0f, 5.0f);
            STEPC(BEE(r6, scur - 6), 0.0f, 5.0f);
            STEPC(BEE(r7, scur - 7), 0.0f, 5.0f);
            scur -= 8;
            r0 = n0; r1 = n1; r2 = n2; r3 = n3;
            r4 = n4; r5 = n5; r6 = n6; r7 = n7;
        }
        STEPC(BEE(r0, 263), 0.0f, 5.0f); STEPC(BEE(r1, 262), 0.0f, 5.0f);
        STEPC(BEE(r2, 261), 0.0f, 5.0f); STEPC(BEE(r3, 260), 0.0f, 5.0f);
        STEPC(BEE(r4, 259), 0.0f, 5.0f); STEPC(BEE(r5, 258), 0.0f, 5.0f);
        STEPC(BEE(r6, 257), 0.0f, 5.0f); STEPC(BEE(r7, 256), 0.0f, 5.0f);
#undef BEE
        ws_state[(size_t)b * 128 + 64 + j] = sc;
    }
#undef STEPC
#undef XCH32
}

// Per-batch wave: logZ = LSE_j(F[j]+U[j]), gold path, diff = logZ - gold.
__global__ __launch_bounds__(64) void crf_combine_kernel(
    const float* __restrict__ emissions,
    const int*   __restrict__ tags,
    const float* __restrict__ mask,
    const float* __restrict__ trans,
    const float* __restrict__ ws_state,
    float* __restrict__ diff_out)
{
    const int b = blockIdx.x;
    const int j = threadIdx.x;
    const float* em = emissions + (size_t)b * SS * TT;
    const float* mk = mask + (size_t)b * SS;

    float v = ws_state[(size_t)b * 128 + j] + ws_state[(size_t)b * 128 + 64 + j];
    float m = v;
    #pragma unroll
    for (int off = 32; off; off >>= 1) m = fmaxf(m, __shfl_xor(m, off));
    float e = __expf(v - m);
    #pragma unroll
    for (int off = 32; off; off >>= 1) e += __shfl_xor(e, off);
    float zres = m + __logf(e);

    float msum = 0.f;
    #pragma unroll
    for (int t = 0; t < 8; ++t) msum += mk[j + 64 * t];
    #pragma unroll
    for (int off = 32; off; off >>= 1) msum += __shfl_xor(msum, off);
    const int len = (int)(first_lane(msum) + 0.5f);

    const int* tg = tags + (size_t)b * SS;
    float acc = 0.f;
    for (int s = j; s < SS; s += 64) {
        if (s < len) {
            if (s > 0) {
                int curr = tg[s], prev = tg[s - 1];
                acc += trans[curr * TSTRIDE + prev] + em[s * TT + curr];
            } else {
                int t0_ = tg[0];
                acc += em[t0_] + trans[t0_ * TSTRIDE + TT];
            }
        }
    }
    #pragma unroll
    for (int off = 32; off; off >>= 1) acc += __shfl_xor(acc, off);
    if (j == 0) {
        int last = tg[len - 1];
        acc += trans[65 * TSTRIDE + last];
        diff_out[b] = zres - acc;
    }
}

__global__ __launch_bounds__(256) void crf_final_kernel(
    const float* __restrict__ diff,
    float* __restrict__ out)
{
    __shared__ float sdata[4];
    int t = threadIdx.x;
    float v = 0.f;
    for (int i = t; i < BB; i += 256) v += diff[i];
    #pragma unroll
    for (int off = 32; off; off >>= 1) v += __shfl_xor(v, off);
    if ((t & 63) == 0) sdata[t >> 6] = v;
    __syncthreads();
    if (t == 0) out[0] = (sdata[0] + sdata[1] + sdata[2] + sdata[3]) * (1.0f / BB);
}

extern "C" void kernel_launch(void* const* d_in, const int* in_sizes, int n_in,
                              void* d_out, int out_size, void* d_ws, size_t ws_size,
                              hipStream_t stream) {
    const float* emissions = (const float*)d_in[0];
    const int*   tags      = (const int*)d_in[1];
    const float* mask      = (const float*)d_in[2];
    const float* trans     = (const float*)d_in[3];
    float* out  = (float*)d_out;
    float* ws_state = (float*)d_ws;             // 512*128 floats
    float* diff = ws_state + (size_t)BB * 128;  // 512 floats

    crf_scan2_kernel<<<2 * BB, 64, 0, stream>>>(emissions, mask, trans, ws_state);
    crf_combine_kernel<<<BB, 64, 0, stream>>>(emissions, tags, mask, trans,
                                              ws_state, diff);
    crf_final_kernel<<<1, 256, 0, stream>>>(diff, out);
}

// Round 11
// 68.144 us; speedup vs baseline: 1.7642x; 1.7642x over previous
//
#include <hip/hip_runtime.h>

#define BB 512
#define SS 512
#define TT 64
#define TSTRIDE 66   // transitions is (66,66)

typedef _Float16 h2 __attribute__((ext_vector_type(2)));
typedef int i2v __attribute__((ext_vector_type(2)));

static __device__ __forceinline__ float first_lane(float v) {
    return __int_as_float(__builtin_amdgcn_readfirstlane(__float_as_int(v)));
}
static __device__ __forceinline__ unsigned pk_f16(float a, float b) {
    return __builtin_bit_cast(unsigned, __builtin_amdgcn_cvt_pkrtz(a, b));
}
static __device__ __forceinline__ h2 as_h2(unsigned u) {
    return __builtin_bit_cast(h2, u);
}
static __device__ __forceinline__ unsigned bperm(int addr, unsigned v) {
    return (unsigned)__builtin_amdgcn_ds_bpermute(addr, (int)v);
}
static __device__ __forceinline__ float swz16f(float v) {   // value from lane^16
    return __int_as_float(__builtin_amdgcn_ds_swizzle(__float_as_int(v), 0x401F));
}
#define FDOT2(a, b, c) __builtin_amdgcn_fdot2((a), (b), (c), false)
#define DPPF(v, ctrl) __int_as_float(__builtin_amdgcn_mov_dpp(__float_as_int(v), (ctrl), 0xF, 0xF, true))
#define DPPU(v, ctrl) ((unsigned)__builtin_amdgcn_mov_dpp((int)(v), (ctrl), 0xF, 0xF, true))

#define DO32(F) F(0) F(1) F(2) F(3) F(4) F(5) F(6) F(7) \
                F(8) F(9) F(10) F(11) F(12) F(13) F(14) F(15) \
                F(16) F(17) F(18) F(19) F(20) F(21) F(22) F(23) \
                F(24) F(25) F(26) F(27) F(28) F(29) F(30) F(31)

// Meet-in-the-middle (R9) + blocked matvec (R11).
// Lane j builds its OWN 16-block of p via the verified DPP tree
// (W_k = {p[j^tl_k], p[j^tl_k^1]}, tl = {0,2,7,5,15,13,8,10}), computes
// 4 column-partials U_m = sum_k dot2(W_k, M{y=j^tl_k / x=j^(m<<4)}), then
// reassembles: sum[j] = (U0 + swz16(U1)) + perm32(U2 + swz16(U3)).
// Cross-lane depth: 2 parallel ds_swizzle + 1 permlane32_swap (~130cy)
// instead of R9's LDS write->read broadcast (~260cy).
// Generic matrix M[x][y]: fwd = trans[y*66+x], bwd = trans[x*66+y];
// E slot (m,k) at lane j = {M[j^(m<<4)][j^tl_k], M[j^(m<<4)][(j^tl_k)^1]}.
__global__ __launch_bounds__(64)
__attribute__((amdgpu_waves_per_eu(1, 1)))
void crf_scan2_kernel(
    const float* __restrict__ emissions,   // [B,S,T]
    const float* __restrict__ mask,        // [B,S]
    const float* __restrict__ trans,       // [66,66]
    float* __restrict__ ws_state)          // [B][128]: F[64] then U[64]
{
    __shared__ unsigned EQ[32][64];        // 8 KB E-fragment staging

    const int blk = blockIdx.x;
    const int b   = blk >> 1;
    const int dir = blk & 1;
    const int j   = threadIdx.x;   // 0..63
    const bool lo32 = (j < 32);
    const int a32v = ((j ^ 32) << 2);      // bpermute fallback address

    const float* em = emissions + (size_t)b * SS * TT;
    const float* mk = mask + (size_t)b * SS;

    // ---- E fragments, pre-permuted for the blocked scheme ----
    {
        const int tl[8] = {0, 2, 7, 5, 15, 13, 8, 10};
        #pragma unroll
        for (int w = 0; w < 32; ++w) {
            int m = w >> 3, k = w & 7;
            int y0 = j ^ tl[k];
            int y1 = y0 ^ 1;
            int x  = j ^ (m << 4);
            if (dir == 0)   // fwd: M[x][y] = trans[y*66 + x]
                EQ[w][j] = pk_f16(__expf(trans[y0 * TSTRIDE + x]),
                                  __expf(trans[y1 * TSTRIDE + x]));
            else            // bwd: M[x][y] = trans[x*66 + y]
                EQ[w][j] = pk_f16(__expf(trans[x * TSTRIDE + y0]),
                                  __expf(trans[x * TSTRIDE + y1]));
        }
    }
    __syncthreads();

#define CDECL(K) const unsigned c##K = EQ[K][j];
    DO32(CDECL)
#undef CDECL

#if defined(__has_builtin) && __has_builtin(__builtin_amdgcn_permlane32_swap)
#define XCH32F(DST, SRC) { i2v r_ = __builtin_amdgcn_permlane32_swap( \
                               __float_as_int(SRC), __float_as_int(SRC), false, false); \
                           DST = __int_as_float(lo32 ? r_.y : r_.x); }
#else
#define XCH32F(DST, SRC) { DST = __int_as_float((int)bperm(a32v, (unsigned)__float_as_int(SRC))); }
#endif

    // PRE folds inside the exp (bwd emission), POST adds after log (fwd).
#define STEPC(PRE, POST, CADD) do { \
        float m0c = first_lane(sc) + (CADD); \
        float p   = __expf(sc + (PRE) - m0c); \
        float pn_ = DPPF(p, 0xB1); \
        unsigned W0 = pk_f16(p, pn_); \
        unsigned W1 = DPPU(W0, 0x4E); \
        unsigned W2 = DPPU(W0, 0x141); \
        unsigned W3 = DPPU(W1, 0x141); \
        unsigned W4 = DPPU(W0, 0x140); \
        unsigned W5 = DPPU(W1, 0x140); \
        unsigned W6 = DPPU(W4, 0x141); \
        unsigned W7 = DPPU(W5, 0x141); \
        float a0_ = 0.f, a1_ = 0.f, a2_ = 0.f, a3_ = 0.f; \
        a0_ = FDOT2(as_h2(W0), as_h2(c0),  a0_); \
        a1_ = FDOT2(as_h2(W0), as_h2(c8),  a1_); \
        a2_ = FDOT2(as_h2(W0), as_h2(c16), a2_); \
        a3_ = FDOT2(as_h2(W0), as_h2(c24), a3_); \
        a0_ = FDOT2(as_h2(W1), as_h2(c1),  a0_); \
        a1_ = FDOT2(as_h2(W1), as_h2(c9),  a1_); \
        a2_ = FDOT2(as_h2(W1), as_h2(c17), a2_); \
        a3_ = FDOT2(as_h2(W1), as_h2(c25), a3_); \
        a0_ = FDOT2(as_h2(W2), as_h2(c2),  a0_); \
        a1_ = FDOT2(as_h2(W2), as_h2(c10), a1_); \
        a2_ = FDOT2(as_h2(W2), as_h2(c18), a2_); \
        a3_ = FDOT2(as_h2(W2), as_h2(c26), a3_); \
        a0_ = FDOT2(as_h2(W3), as_h2(c3),  a0_); \
        a1_ = FDOT2(as_h2(W3), as_h2(c11), a1_); \
        a2_ = FDOT2(as_h2(W3), as_h2(c19), a2_); \
        a3_ = FDOT2(as_h2(W3), as_h2(c27), a3_); \
        a0_ = FDOT2(as_h2(W4), as_h2(c4),  a0_); \
        a1_ = FDOT2(as_h2(W4), as_h2(c12), a1_); \
        a2_ = FDOT2(as_h2(W4), as_h2(c20), a2_); \
        a3_ = FDOT2(as_h2(W4), as_h2(c28), a3_); \
        a0_ = FDOT2(as_h2(W5), as_h2(c5),  a0_); \
        a1_ = FDOT2(as_h2(W5), as_h2(c13), a1_); \
        a2_ = FDOT2(as_h2(W5), as_h2(c21), a2_); \
        a3_ = FDOT2(as_h2(W5), as_h2(c29), a3_); \
        a0_ = FDOT2(as_h2(W6), as_h2(c6),  a0_); \
        a1_ = FDOT2(as_h2(W6), as_h2(c14), a1_); \
        a2_ = FDOT2(as_h2(W6), as_h2(c22), a2_); \
        a3_ = FDOT2(as_h2(W6), as_h2(c30), a3_); \
        a0_ = FDOT2(as_h2(W7), as_h2(c7),  a0_); \
        a1_ = FDOT2(as_h2(W7), as_h2(c15), a1_); \
        a2_ = FDOT2(as_h2(W7), as_h2(c23), a2_); \
        a3_ = FDOT2(as_h2(W7), as_h2(c31), a3_); \
        float V0 = a0_ + swz16f(a1_); \
        float V1 = a2_ + swz16f(a3_); \
        float Vx; XCH32F(Vx, V1); \
        float sum_ = V0 + Vx; \
        sc = m0c + __logf(sum_) + (POST); \
    } while (0)

    float sc;
    if (dir == 0) {
        // ---------- forward: steps 1..255, no mask (len >= 256) ----------
        sc = em[j] + trans[j * TSTRIDE + TT];   // score0 (mask[0]==1)
        float r0 = em[1 * TT + j], r1 = em[2 * TT + j];
        float r2 = em[3 * TT + j], r3 = em[4 * TT + j];
        float r4 = em[5 * TT + j], r5 = em[6 * TT + j];
        float r6 = em[7 * TT + j], r7 = em[8 * TT + j];
        const float* pe = em + 9 * TT + j;
        for (int it = 0; it < 31; ++it) {       // steps 1..248
            float n0 = pe[0],   n1 = pe[64],  n2 = pe[128], n3 = pe[192];
            float n4 = pe[256], n5 = pe[320], n6 = pe[384], n7 = pe[448];
            pe += 512;
            STEPC(0.0f, r0, 4.0f); STEPC(0.0f, r1, 4.0f);
            STEPC(0.0f, r2, 4.0f); STEPC(0.0f, r3, 4.0f);
            STEPC(0.0f, r4, 4.0f); STEPC(0.0f, r5, 4.0f);
            STEPC(0.0f, r6, 4.0f); STEPC(0.0f, r7, 4.0f);
            r0 = n0; r1 = n1; r2 = n2; r3 = n3;
            r4 = n4; r5 = n5; r6 = n6; r7 = n7;
        }
        STEPC(0.0f, r0, 4.0f); STEPC(0.0f, r1, 4.0f);   // steps 249..255
        STEPC(0.0f, r2, 4.0f); STEPC(0.0f, r3, 4.0f);
        STEPC(0.0f, r4, 4.0f); STEPC(0.0f, r5, 4.0f);
        STEPC(0.0f, r6, 4.0f);
        ws_state[(size_t)b * 128 + j] = sc;
    } else {
        // ---------- backward: steps 511..256 ----------
        float msum = 0.f;
        #pragma unroll
        for (int t = 0; t < 8; ++t) msum += mk[j + 64 * t];
        #pragma unroll
        for (int off = 32; off; off >>= 1) msum += __shfl_xor(msum, off);
        const int len = (int)(first_lane(msum) + 0.5f);

        sc = trans[65 * TSTRIDE + j];           // u_511 = stop vector
        float r0 = em[511 * TT + j], r1 = em[510 * TT + j];
        float r2 = em[509 * TT + j], r3 = em[508 * TT + j];
        float r4 = em[507 * TT + j], r5 = em[506 * TT + j];
        float r6 = em[505 * TT + j], r7 = em[504 * TT + j];
        const float* pe = em + 503 * TT + j;
        int scur = 511;
#define BEE(RK, SV) (((SV) < len) ? (RK) : 0.0f)
        for (int it = 0; it < 31; ++it) {       // steps 511..264
            float n0 = pe[0],    n1 = pe[-64],  n2 = pe[-128], n3 = pe[-192];
            float n4 = pe[-256], n5 = pe[-320], n6 = pe[-384], n7 = pe[-448];
            pe -= 512;
            STEPC(BEE(r0, scur - 0), 0.0f, 5.0f);
            STEPC(BEE(r1, scur - 1), 0.0f, 5.0f);
            STEPC(BEE(r2, scur - 2), 0.0f, 5.0f);
            STEPC(BEE(r3, scur - 3), 0.0f, 5.0f);
            STEPC(BEE(r4, scur - 4), 0.0f, 5.0f);
            STEPC(BEE(r5, scur - 5), 0.0f, 5.0f);
            STEPC(BEE(r6, scur - 6), 0.0f, 5.0f);
            STEPC(BEE(r7, scur - 7), 0.0f, 5.0f);
            scur -= 8;
            r0 = n0; r1 = n1; r2 = n2; r3 = n3;
            r4 = n4; r5 = n5; r6 = n6; r7 = n7;
        }
        STEPC(BEE(r0, 263), 0.0f, 5.0f); STEPC(BEE(r1, 262), 0.0f, 5.0f);
        STEPC(BEE(r2, 261), 0.0f, 5.0f); STEPC(BEE(r3, 260), 0.0f, 5.0f);
        STEPC(BEE(r4, 259), 0.0f, 5.0f); STEPC(BEE(r5, 258), 0.0f, 5.0f);
        STEPC(BEE(r6, 257), 0.0f, 5.0f); STEPC(BEE(r7, 256), 0.0f, 5.0f);
#undef BEE
        ws_state[(size_t)b * 128 + 64 + j] = sc;
    }
#undef STEPC
#undef XCH32F
}

// Per-batch wave: logZ = LSE_j(F[j]+U[j]), gold path, diff = logZ - gold.
__global__ __launch_bounds__(64) void crf_combine_kernel(
    const float* __restrict__ emissions,
    const int*   __restrict__ tags,
    const float* __restrict__ mask,
    const float* __restrict__ trans,
    const float* __restrict__ ws_state,
    float* __restrict__ diff_out)
{
    const int b = blockIdx.x;
    const int j = threadIdx.x;
    const float* em = emissions + (size_t)b * SS * TT;
    const float* mk = mask + (size_t)b * SS;

    float v = ws_state[(size_t)b * 128 + j] + ws_state[(size_t)b * 128 + 64 + j];
    float m = v;
    #pragma unroll
    for (int off = 32; off; off >>= 1) m = fmaxf(m, __shfl_xor(m, off));
    float e = __expf(v - m);
    #pragma unroll
    for (int off = 32; off; off >>= 1) e += __shfl_xor(e, off);
    float zres = m + __logf(e);

    float msum = 0.f;
    #pragma unroll
    for (int t = 0; t < 8; ++t) msum += mk[j + 64 * t];
    #pragma unroll
    for (int off = 32; off; off >>= 1) msum += __shfl_xor(msum, off);
    const int len = (int)(first_lane(msum) + 0.5f);

    const int* tg = tags + (size_t)b * SS;
    float acc = 0.f;
    for (int s = j; s < SS; s += 64) {
        if (s < len) {
            if (s > 0) {
                int curr = tg[s], prev = tg[s - 1];
                acc += trans[curr * TSTRIDE + prev] + em[s * TT + curr];
            } else {
                int t0_ = tg[0];
                acc += em[t0_] + trans[t0_ * TSTRIDE + TT];
            }
        }
    }
    #pragma unroll
    for (int off = 32; off; off >>= 1) acc += __shfl_xor(acc, off);
    if (j == 0) {
        int last = tg[len - 1];
        acc += trans[65 * TSTRIDE + last];
        diff_out[b] = zres - acc;
    }
}

__global__ __launch_bounds__(256) void crf_final_kernel(
    const float* __restrict__ diff,
    float* __restrict__ out)
{
    __shared__ float sdata[4];
    int t = threadIdx.x;
    float v = 0.f;
    for (int i = t; i < BB; i += 256) v += diff[i];
    #pragma unroll
    for (int off = 32; off; off >>= 1) v += __shfl_xor(v, off);
    if ((t & 63) == 0) sdata[t >> 6] = v;
    __syncthreads();
    if (t == 0) out[0] = (sdata[0] + sdata[1] + sdata[2] + sdata[3]) * (1.0f / BB);
}

extern "C" void kernel_launch(void* const* d_in, const int* in_sizes, int n_in,
                              void* d_out, int out_size, void* d_ws, size_t ws_size,
                              hipStream_t stream) {
    const float* emissions = (const float*)d_in[0];
    const int*   tags      = (const int*)d_in[1];
    const float* mask      = (const float*)d_in[2];
    const float* trans     = (const float*)d_in[3];
    float* out  = (float*)d_out;
    float* ws_state = (float*)d_ws;             // 512*128 floats
    float* diff = ws_state + (size_t)BB * 128;  // 512 floats

    crf_scan2_kernel<<<2 * BB, 64, 0, stream>>>(emissions, mask, trans, ws_state);
    crf_combine_kernel<<<BB, 64, 0, stream>>>(emissions, tags, mask, trans,
                                              ws_state, diff);
    crf_final_kernel<<<1, 256, 0, stream>>>(diff, out);
}